// Round 7
// baseline (674.730 us; speedup 1.0000x reference)
//
#include <hip/hip_runtime.h>
#include <stdint.h>
#include <stddef.h>

// C[4096,11008] = X[4096,4096] @ W^T, W = int4 group-128 dequant.
// R10: R5/R7/R8/R9 2x2 complete: wait-discipline and read-pipelining each
// worth ~0; all land 365-388us. Accounting: per 2 K-tiles MFMA pipe needs
// ~4970cy, LDS reads ~2300cy, measured ~10200cy at 8 phases -> the cost is
// PER-PHASE overhead (barrier straggle + lgkm settle + setprio churn) ~= the
// 310cy/wave MFMA cluster itself. Fix: coarser phases + faster pipe:
//  - mfma_f32_32x32x16_f16 (ubench 2495 vs 2075 TF for 16x16 -> -17% pipe cy)
//  - phase = one 32-k section = 16 MFMA of 32x32x16 (2x FLOP/phase);
//    4 phases + 4 barriers per 2 K-tiles (was 8).
//  - slot cycle period-4: phase p computes sec p (regs read at p-1), reads
//    sec p+1 from slot (p+1)%4, stages sec p+3 into slot (p+3)%4, vmcnt(4)
//    retires sec p+2's group (read next phase), bar. Wait BEFORE barrier on
//    all waves (R6 lesson). Outstanding 8->4, never 0.
// Staging/LDS layout/swizzle byte-identical to R9 (verified): fragment reads
// re-derived for 32-row fragments: per 16-lane group 8 slot-positions x2 =
// 2-way = free. 32x32 C/D: col=lane&31, row=(reg&3)+8*(reg>>2)+4*(lane>>5)
// (doc-verified m74/m101); A/B: row=lane&31, k=(lane>>5)*8+i (scaled from our
// verified 16x16x32 mapping).

#define M_TOK 4096
#define K_IN  4096
#define N_OUT 11008
#define NGRP  32

#define MTI 16            // 4096/256
#define NTI 43            // 11008/256
#define TILES (MTI * NTI) // 688 = 8*86

#define BH_OFF ((size_t)M_TOK * K_IN * 2)   // Ah: 32 MiB, then Bh: 86 MiB

typedef _Float16 h8v __attribute__((ext_vector_type(8)));
typedef float    fx16 __attribute__((ext_vector_type(16)));

__device__ __forceinline__ void gload16(const void* g, void* l) {
  __builtin_amdgcn_global_load_lds(
      (__attribute__((address_space(1))) void*)(g),
      (__attribute__((address_space(3))) void*)(l),
      16, 0, 0);
}

// Clean counted waits: NO memory clobbers.
#define WAIT_VM4 asm volatile("s_waitcnt vmcnt(4)")
#define WAIT_VM0 asm volatile("s_waitcnt vmcnt(0)")
#define BAR __builtin_amdgcn_s_barrier()

// ---- prepass 1: X f32 -> f16, natural order ----
__global__ __launch_bounds__(256) void cvt_x_kernel(const float* __restrict__ x,
                                                    _Float16* __restrict__ xh) {
  size_t t = (size_t)blockIdx.x * 256 + threadIdx.x;
  const float4* s = (const float4*)x + t * 2;
  float4 a = s[0], b = s[1];
  h8v o;
  o[0] = (_Float16)a.x; o[1] = (_Float16)a.y; o[2] = (_Float16)a.z; o[3] = (_Float16)a.w;
  o[4] = (_Float16)b.x; o[5] = (_Float16)b.y; o[6] = (_Float16)b.z; o[7] = (_Float16)b.w;
  ((h8v*)xh)[t] = o;
}

// ---- prepass 2: full dequant W -> f16 [OUT][IN], natural order ----
__global__ __launch_bounds__(256) void dequant_w_kernel(const int* __restrict__ wp,
                                                        const float* __restrict__ ws,
                                                        const int* __restrict__ wz,
                                                        _Float16* __restrict__ bh) {
  size_t tg = (size_t)blockIdx.x * 256 + threadIdx.x;
  int j   = (int)(tg & 127);
  int row = (int)(tg >> 7);
  int g = j >> 2;
  float s = ws[(size_t)row * NGRP + g];
  float c = -s * (8.0f + (float)wz[(size_t)row * NGRP + g]);
  const int4* src = (const int4*)(wp + (size_t)row * 2048 + j * 16);
  _Float16* dst = bh + (size_t)row * 4096 + j * 32;
#pragma unroll
  for (int b = 0; b < 4; ++b) {
    int4 v = src[b];
    int q[4] = {v.x, v.y, v.z, v.w};
    h8v o;
#pragma unroll
    for (int i = 0; i < 4; ++i) {
      int lo = (q[i] & 15) ^ 8;
      int hi = ((q[i] >> 4) & 15) ^ 8;
      o[2 * i]     = (_Float16)(s * (float)lo + c);
      o[2 * i + 1] = (_Float16)(s * (float)hi + c);
    }
    ((h8v*)dst)[b] = o;
  }
}

// ---- GEMM: 256x256 tile, 8 waves (2M x 4N), 32x32x16 MFMA, 4-slot ring ----
// LDS: 4 section-slots of 32KB (A 16KB + B 16KB); slot k: A @ (k>>1)*65536 +
// (k&1)*16384, B @ +32768. Section = 32 k-columns.
// byte(row,kchunk) = slotA + (row*4 + (kchunk ^ ((row>>1)&3)))*16
#define ABASE(S) (((S) >> 1) * 65536 + ((S) & 1) * 16384)

__global__ __launch_bounds__(512, 2) void gemm_kernel(
    const _Float16* __restrict__ Ah,
    const _Float16* __restrict__ Bh,
    float* __restrict__ C) {
  __shared__ __align__(128) char smem[131072];

  const int bid = blockIdx.x;
  // XCD swizzle, bijective (688 = 8*86)
  const int swz = (bid & 7) * 86 + (bid >> 3);
  const int mt = swz / NTI;
  const int nt = swz - mt * NTI;
  const int m0 = mt * 256;
  const int n0 = nt * 256;

  const int tid  = threadIdx.x;
  const int lane = tid & 63;
  const int wid  = tid >> 6;
  const int wm   = wid >> 2;   // 0..1
  const int wn   = wid & 3;    // 0..3

  const int lrow32 = lane & 31;
  const int hi     = lane >> 5;            // k-octet selector
  const int msk    = (lrow32 >> 1) & 3;    // LDS slot swizzle mask
  const int suk0   = hi ^ msk;             // ks=0 chunk slot
  const int suk1   = (2 + hi) ^ msk;       // ks=1 chunk slot
  const int arow   = wm * 128 + lrow32;    // + mi*32
  const int brow   = wn * 64 + lrow32;     // + ni*32

  // staging (identical to R9, verified): thread covers rows r0, r0+16,
  // one pre-swizzled 16B global kchunk each; linear gload_lds dest.
  const int r0 = wid * 32 + (lane >> 2);
  const int kc = (lane & 3) ^ ((lane >> 3) & 3);
  const size_t gA0 = (size_t)(m0 + r0) * K_IN + kc * 8;
  const size_t gB0 = (size_t)(n0 + r0) * K_IN + kc * 8;
  const int ldsl = wid * 2048;  // + j*1024

  fx16 acc[4][2];
#pragma unroll
  for (int i = 0; i < 4; ++i)
#pragma unroll
    for (int j = 0; j < 2; ++j)
      acc[i][j] = (fx16){0.f,0.f,0.f,0.f,0.f,0.f,0.f,0.f,
                         0.f,0.f,0.f,0.f,0.f,0.f,0.f,0.f};

  h8v afa[8], afb[8], bfa[4], bfb[4];

// stage A+B 16KB halves of section SEC -> slot SLOT (4 gload_lds)
#define STG(SLOT, SEC)                                                         \
  { const _Float16* gA_ = Ah + gA0 + (size_t)(SEC) * 32;                       \
    const _Float16* gB_ = Bh + gB0 + (size_t)(SEC) * 32;                       \
    char* lA_ = smem + ABASE(SLOT) + ldsl;                                     \
    gload16(gA_, lA_);                                                         \
    gload16(gA_ + 16 * K_IN, lA_ + 1024);                                      \
    gload16(gB_, lA_ + 32768);                                                 \
    gload16(gB_ + 16 * K_IN, lA_ + 32768 + 1024); }

#define RD_A(DST, SLOT)                                                        \
  { const char* s_ = smem + ABASE(SLOT);                                       \
    _Pragma("unroll")                                                          \
    for (int mi_ = 0; mi_ < 4; ++mi_) {                                        \
      DST[mi_ * 2 + 0] = *(const h8v*)(s_ + ((arow + mi_ * 32) * 4 + suk0) * 16); \
      DST[mi_ * 2 + 1] = *(const h8v*)(s_ + ((arow + mi_ * 32) * 4 + suk1) * 16); \
    } }

#define RD_B(DST, SLOT)                                                        \
  { const char* s_ = smem + ABASE(SLOT) + 32768;                               \
    _Pragma("unroll")                                                          \
    for (int ni_ = 0; ni_ < 2; ++ni_) {                                        \
      DST[ni_ * 2 + 0] = *(const h8v*)(s_ + ((brow + ni_ * 32) * 4 + suk0) * 16); \
      DST[ni_ * 2 + 1] = *(const h8v*)(s_ + ((brow + ni_ * 32) * 4 + suk1) * 16); \
    } }

// 16 x mfma_f32_32x32x16_f16 over one 32-k section (ks-major)
#define MM(AF, BF)                                                             \
  { __builtin_amdgcn_s_setprio(1);                                             \
    _Pragma("unroll")                                                          \
    for (int ks_ = 0; ks_ < 2; ++ks_)                                          \
      _Pragma("unroll")                                                        \
      for (int mi_ = 0; mi_ < 4; ++mi_)                                        \
        _Pragma("unroll")                                                      \
        for (int ni_ = 0; ni_ < 2; ++ni_)                                      \
          acc[mi_][ni_] = __builtin_amdgcn_mfma_f32_32x32x16_f16(              \
              AF[mi_ * 2 + ks_], BF[ni_ * 2 + ks_], acc[mi_][ni_], 0, 0, 0);   \
    __builtin_amdgcn_s_setprio(0); }

  // prologue: sections 0,1,2 -> slots 0,1,2; vmcnt(4) retires sec0+sec1 on
  // all waves; barrier publishes; pre-read sec0 fragments.
  STG(0, 0);
  STG(1, 1);
  STG(2, 2);
  WAIT_VM4;
  BAR;
  RD_A(afa, 0);
  RD_B(bfa, 0);

  // 128 sections, 4 phases/iter. Phase p: MFMA sec p (prev-phase regs);
  // read sec p+1; stage sec p+3; vmcnt(4) retires sec p+2's group; bar.
  for (int s = 0; s < 128; s += 4) {
    const int s4 = (s + 4 < 128) ? s + 4 : 127;  // tail: dummy restage, dead
    const int s5 = (s + 5 < 128) ? s + 5 : 127;
    const int s6 = (s + 6 < 128) ? s + 6 : 127;
    // ph0: sec s
    RD_A(afb, 1); RD_B(bfb, 1); STG(3, s + 3); MM(afa, bfa); WAIT_VM4; BAR;
    // ph1: sec s+1
    RD_A(afa, 2); RD_B(bfa, 2); STG(0, s4);    MM(afb, bfb); WAIT_VM4; BAR;
    // ph2: sec s+2
    RD_A(afb, 3); RD_B(bfb, 3); STG(1, s5);    MM(afa, bfa); WAIT_VM4; BAR;
    // ph3: sec s+3
    RD_A(afa, 0); RD_B(bfa, 0); STG(2, s6);    MM(afb, bfb); WAIT_VM4; BAR;
  }
  WAIT_VM0;  // drain dummy stages before epilogue/endpgm

  // epilogue: 32x32 C/D layout col = lane&31 (n), row = (r&3)+8*(r>>2)+4*hi
#pragma unroll
  for (int mi = 0; mi < 4; ++mi) {
#pragma unroll
    for (int ni = 0; ni < 2; ++ni) {
#pragma unroll
      for (int r = 0; r < 16; ++r) {
        int m = m0 + wm * 128 + mi * 32 + (r & 3) + 8 * (r >> 2) + 4 * hi;
        C[(size_t)m * N_OUT + n0 + wn * 64 + ni * 32 + lrow32] = acc[mi][ni][r];
      }
    }
  }
#undef MM
#undef RD_B
#undef RD_A
#undef STG
}

extern "C" void kernel_launch(void* const* d_in, const int* in_sizes, int n_in,
                              void* d_out, int out_size, void* d_ws, size_t ws_size,
                              hipStream_t stream) {
  const float* x   = (const float*)d_in[0];
  const int*   wp  = (const int*)d_in[1];
  const float* wsc = (const float*)d_in[2];
  const int*   wz  = (const int*)d_in[3];

  _Float16* Ah = (_Float16*)d_ws;
  _Float16* Bh = (_Float16*)((char*)d_ws + BH_OFF);

  cvt_x_kernel<<<(M_TOK * (size_t)K_IN) / (8 * 256), 256, 0, stream>>>(x, Ah);
  dequant_w_kernel<<<((size_t)N_OUT * 128) / 256, 256, 0, stream>>>(wp, wsc, wz, Bh);
  gemm_kernel<<<TILES, 512, 0, stream>>>(Ah, Bh, (float*)d_out);
}